// Round 4
// baseline (336.457 us; speedup 1.0000x reference)
//
#include <hip/hip_runtime.h>

#define TT 512
#define DD 16
#define HH 30
#define LL 10
#define NB 2                  // batches per block
#define C  4                  // timesteps per phase (chunk)
#define TCH (TT / C)          // 128 chunks
#define PH (TCH + LL - 1)     // 137 phases
#define ROWH 40               // halfs per row (80 B): [data 0..31 | pad]

typedef _Float16 h2 __attribute__((ext_vector_type(2)));

__device__ __forceinline__ float tanh_fast(float x) {
    // tanh(x) = 1 - 2/(exp(2x)+1); saturates correctly at +-inf
    float e = __expf(2.0f * x);
    return 1.0f - 2.0f * __builtin_amdgcn_rcpf(e + 1.0f);
}

#if __has_builtin(__builtin_amdgcn_fdot2)
#define DOT2(a, b, c) __builtin_amdgcn_fdot2((a), (b), (c), false)
#else
__device__ __forceinline__ float DOT2(h2 a, h2 b, float c) {
    return fmaf((float)a.x, (float)b.x, fmaf((float)a.y, (float)b.y, c));
}
#endif

__device__ __forceinline__ h2 asH2(unsigned u) {
    union { unsigned u; h2 h; } v; v.u = u; return v.h;
}

__global__ __launch_bounds__(640, 5) void rnn_pipe16b(
    const float* __restrict__ x,   const float* __restrict__ wi0,
    const float* __restrict__ wih, const float* __restrict__ whh,
    const float* __restrict__ bih, const float* __restrict__ bhh,
    const float* __restrict__ fcw, const float* __restrict__ fcb,
    float* __restrict__ out)
{
    // act[parity][layer][cc][bb]: INPUT row for layer at chunk-step cc.
    //   halfs 0..31 = data (layer0: x(16)+pad; else h(30)+pad), rest pad.
    // own[layer][bb]: layer's own h (same-wave producer/consumer, no parity).
    __shared__ __align__(16) _Float16 act[2][LL][C][NB][ROWH];
    __shared__ __align__(16) _Float16 own[LL][NB][ROWH];

    const int tid  = threadIdx.x;
    const int l    = tid >> 6;        // wave == layer
    const int lane = tid & 63;
    const int bb   = lane >> 5;       // batch slot 0..1
    const int g    = lane & 31;       // neuron (g<30 active)
    const int gm   = (g < HH) ? g : HH - 1;
    const int batch = blockIdx.x * NB + bb;

    // ---- pack this layer's weight row `gm` into h2 registers ----
    // words 0..15: input weights (layer0: 16 x-weights+pad; else 30 h + pad)
    // words 16..31: own-recurrence weights (30 + pad)
    h2 w[32];
    #pragma unroll
    for (int c = 0; c < 16; ++c) {
        const int k0 = 2 * c, k1 = 2 * c + 1;
        float a0 = 0.f, a1 = 0.f;
        if (l == 0) {
            if (k0 < DD) a0 = wi0[gm * DD + k0];
            if (k1 < DD) a1 = wi0[gm * DD + k1];
        } else {
            if (k0 < HH) a0 = wih[(l-1)*900 + gm*HH + k0];
            if (k1 < HH) a1 = wih[(l-1)*900 + gm*HH + k1];
        }
        w[c] = h2{(_Float16)a0, (_Float16)a1};
    }
    #pragma unroll
    for (int c = 0; c < 16; ++c) {
        const int k0 = 2 * c, k1 = 2 * c + 1;
        float a0 = 0.f, a1 = 0.f;
        if (k0 < HH) a0 = whh[l*900 + gm*HH + k0];
        if (k1 < HH) a1 = whh[l*900 + gm*HH + k1];
        w[16 + c] = h2{(_Float16)a0, (_Float16)a1};
    }
    const float bc = bih[l * HH + gm] + bhh[l * HH + gm];
    float fw = 0.f, fbv = 0.f;
    if (l == LL - 1) { fw = (g < HH) ? fcw[gm] : 0.f; fbv = fcb[0]; }

    // ---- zero LDS (pads must stay true zero; h(-1)=0) ----
    {
        unsigned* za = (unsigned*)&act[0][0][0][0][0];
        const int na = sizeof(act) / 4;
        for (int i = tid; i < na; i += 640) za[i] = 0u;
        unsigned* zo = (unsigned*)&own[0][0][0];
        const int no = sizeof(own) / 4;
        for (int i = tid; i < no; i += 640) zo[i] = 0u;
    }
    __syncthreads();

    // ---- x staging lane map (wave 0): lane = sc*16 + sbb*8 + sq ----
    // each lane loads float2 (d = 2*sq, 2*sq+1) for (chunk-step sc, batch sbb)
    const int sq  = lane & 7;
    const int sbb = (lane >> 3) & 1;
    const int sc  = lane >> 4;
    const int batch_s = blockIdx.x * NB + sbb;
    const float2* xb2 = (const float2*)x;

    // prestage x chunk 0 (t=0..3) into parity-1 rows
    if (l == 0) {
        float2 v = xb2[batch_s * TT * (DD/2) + sc * (DD/2) + sq];
        *(h2*)&act[1][0][sc][sbb][2 * sq] = h2{(_Float16)v.x, (_Float16)v.y};
    }

    float hl = 0.f;                   // wave 9 keeps h(T-1) for FC

    for (int p = 0; p < PH; ++p) {
        const int q  = (p + 1) & 1;   // read parity
        const int wp = p & 1;         // write parity
        const int pt = p - l;         // this wave's chunk index

        // wave 0: issue next chunk's x loads early (hidden under compute)
        float2 xv;
        const bool dost = (l == 0) && (p + 1 < TCH);
        if (dost)
            xv = xb2[batch_s * TT * (DD/2) + ((p + 1) * C + sc) * (DD/2) + sq];

        if (0 <= pt && pt < TCH) {
            #pragma unroll
            for (int cc = 0; cc < C; ++cc) {
                const uint4* ir = (const uint4*)&act[q][l][cc][bb][0];
                const uint4 A = ir[0], B = ir[1], Cw = ir[2], Dw = ir[3];
                const uint4* orr = (const uint4*)&own[l][bb][0];
                const uint4 E = orr[0], F = orr[1], G = orr[2], Hh = orr[3];
                const unsigned wv[32] = {
                    A.x,A.y,A.z,A.w,  B.x,B.y,B.z,B.w,
                    Cw.x,Cw.y,Cw.z,Cw.w, Dw.x,Dw.y,Dw.z,Dw.w,
                    E.x,E.y,E.z,E.w,  F.x,F.y,F.z,F.w,
                    G.x,G.y,G.z,G.w,  Hh.x,Hh.y,Hh.z,Hh.w };
                float a = bc;
                #pragma unroll
                for (int c = 0; c < 32; ++c)
                    a = DOT2(w[c], asH2(wv[c]), a);
                const float h = tanh_fast(a);
                const _Float16 hh = (_Float16)h;
                if (g < HH) {
                    own[l][bb][g] = hh;                 // own h for t+1
                    if (l < LL - 1)
                        act[wp][l + 1][cc][bb][g] = hh; // next layer's input
                }
                hl = h;
            }
        }

        // wave 0: convert + write staged x rows for next chunk
        if (dost)
            *(h2*)&act[wp][0][sc][sbb][2 * sq] = h2{(_Float16)xv.x, (_Float16)xv.y};

        __syncthreads();
    }

    // ---- FC on h_{L-1}(T-1): out[b] = fcw . h + fcb ----
    if (l == LL - 1) {
        float v = (g < HH) ? hl * fw : 0.f;
        v += __shfl_xor(v, 1);
        v += __shfl_xor(v, 2);
        v += __shfl_xor(v, 4);
        v += __shfl_xor(v, 8);
        v += __shfl_xor(v, 16);
        if (g == 0) out[batch] = v + fbv;
    }
}

extern "C" void kernel_launch(void* const* d_in, const int* in_sizes, int n_in,
                              void* d_out, int out_size, void* d_ws, size_t ws_size,
                              hipStream_t stream) {
    const float* x   = (const float*)d_in[0];
    const float* wi0 = (const float*)d_in[1];
    const float* wih = (const float*)d_in[2];
    const float* whh = (const float*)d_in[3];
    const float* bih = (const float*)d_in[4];
    const float* bhh = (const float*)d_in[5];
    const float* fcw = (const float*)d_in[6];
    const float* fcb = (const float*)d_in[7];
    float* out = (float*)d_out;

    rnn_pipe16b<<<1024 / NB, 640, 0, stream>>>(x, wi0, wih, whh, bih, bhh,
                                               fcw, fcb, out);
}